// Round 16
// baseline (68.741 us; speedup 1.0000x reference)
//
#include <hip/hip_runtime.h>
#include <math.h>

#define NN 100000
#define EE 1600000
#define HH 128
#define RR 500
#define AA 16
#define LN_EPS 1e-5f

// Bucketing: nodes -> 391 buckets of 256; payload packs (src<<8 | dst&255) in u32.
#define BSH 8
#define NPB 256
#define NB 391                   // ceil(100000/256)
#define MAXPB 4608               // mean 4096, +8 sigma
#define EPW 8192                 // edges per scatter workgroup
#define SCT 512                  // scatter threads
#define NWG_SC ((EE + EPW - 1) / EPW)   // 196
#define NZW 16                   // zpart slices (32 k-rows each, covers 500)
#define BAT 512                  // bagg threads
#define NSREP 8                  // S/T2 replicas
#define NTW 16                   // tail1 WGs (8 k-rows of fc1_w[0:128] each)

// WG0: zero gctr/S8/T2_8. WGs 1..16: zpart[sl] = sum_{k in slice} esn[k]*fc1_w[(HH+k)*HH+:]
__global__ __launch_bounds__(256) void k_init_esn(unsigned int* __restrict__ zero_region,
                                                  const float* __restrict__ esn,
                                                  const float* __restrict__ fc1_w,
                                                  float* __restrict__ zpart) {
    const int w = blockIdx.x, t = threadIdx.x;
    if (w == 0) {
        for (int j = t; j < 1544; j += 256) zero_region[j] = 0u;   // gctr|S8|T2_8
        return;
    }
    const int sl = w - 1;                 // 0..15
    const int k0 = sl * 32;
    const int k1 = min(k0 + 32, RR);
    if (t < HH) {
        float acc = 0.f;
        for (int k = k0; k < k1; ++k)
            acc = fmaf(esn[k], fc1_w[(size_t)(HH + k) * HH + t], acc);
        zpart[(size_t)sl * HH + t] = acc;
    }
}

// Bucket edges by dst — single LDS-atomic pass (rank yields slot AND count).
__global__ __launch_bounds__(SCT) void k_scatter(const int* __restrict__ src,
                                                 const int* __restrict__ dst,
                                                 unsigned int* __restrict__ gctr,
                                                 unsigned int* __restrict__ payload) {
    __shared__ unsigned int rank[512], hbase[512];
    const int t = threadIdx.x;
    rank[t] = 0u; hbase[t] = 0u;
    __syncthreads();
    const int e0 = blockIdx.x * EPW;
    const int ecnt = max(0, min(EPW, EE - e0));   // mult of 4
    const int nv = ecnt >> 2;
    const int4* d4 = reinterpret_cast<const int4*>(dst + e0);
    const int4* s4 = reinterpret_cast<const int4*>(src + e0);

    unsigned int pw[16], pbr[16];
    bool vk[4];

    #pragma unroll
    for (int kk = 0; kk < 4; ++kk) {
        const int k = t + kk * SCT;
        vk[kk] = (k < nv);
        if (vk[kk]) {
            int4 d = d4[k];
            int4 s = s4[k];
            #define GRAB(i, SS, DD) { \
                unsigned int dd = (unsigned)(DD), ss = (unsigned)(SS); \
                unsigned int b = dd >> BSH; \
                unsigned int r = atomicAdd(&rank[b], 1u); \
                pw[kk * 4 + i]  = (ss << BSH) | (dd & (NPB - 1)); \
                pbr[kk * 4 + i] = (b << 16) | (r & 0xFFFFu); }
            GRAB(0, s.x, d.x) GRAB(1, s.y, d.y) GRAB(2, s.z, d.z) GRAB(3, s.w, d.w)
            #undef GRAB
        }
    }
    __syncthreads();

    if (t < NB && rank[t] > 0u) hbase[t] = atomicAdd(&gctr[t], rank[t]);
    __syncthreads();

    #pragma unroll
    for (int kk = 0; kk < 4; ++kk) {
        if (vk[kk]) {
            #define PUT(i) { \
                unsigned int b = pbr[kk * 4 + i] >> 16; \
                unsigned int slot = hbase[b] + (pbr[kk * 4 + i] & 0xFFFFu); \
                if (slot < MAXPB) payload[(size_t)b * MAXPB + slot] = pw[kk * 4 + i]; }
            PUT(0) PUT(1) PUT(2) PUT(3)
            #undef PUT
        }
    }
}

// Per bucket, 1024 threads: LDS degree histogram; write rsv = rsqrt(deg), g = rsv*f.
__global__ __launch_bounds__(1024) void k_bdeg_g(const unsigned int* __restrict__ gctr,
                                                 const unsigned int* __restrict__ payload,
                                                 const float* __restrict__ nf,
                                                 float* __restrict__ rsv, float* __restrict__ g) {
    __shared__ unsigned int hist[NPB];
    const int b = blockIdx.x, t = threadIdx.x;
    if (t < NPB) hist[t] = 0u;
    __syncthreads();
    const unsigned int cnt = min(gctr[b], (unsigned int)MAXPB);
    const unsigned int* pl = payload + (size_t)b * MAXPB;
    const uint4* pl4 = reinterpret_cast<const uint4*>(pl);
    const unsigned int nv = cnt >> 2;
    for (unsigned int k = t; k < nv; k += 1024) {
        uint4 p = pl4[k];
        atomicAdd(&hist[p.x & (NPB - 1)], 1u);
        atomicAdd(&hist[p.y & (NPB - 1)], 1u);
        atomicAdd(&hist[p.z & (NPB - 1)], 1u);
        atomicAdd(&hist[p.w & (NPB - 1)], 1u);
    }
    for (unsigned int k = (nv << 2) + t; k < cnt; k += 1024)
        atomicAdd(&hist[pl[k] & (NPB - 1)], 1u);
    __syncthreads();
    if (t < NPB) {
        int node = (b << BSH) + t;
        if (node < NN) {
            float df = 1.0f + (float)hist[t];
            float rs = rsqrtf(df);
            rsv[node] = rs;
            float2 f = *reinterpret_cast<const float2*>(&nf[2 * node]);
            float2 gv; gv.x = rs * f.x; gv.y = rs * f.y;
            *reinterpret_cast<float2*>(&g[2 * node]) = gv;
        }
    }
}

// Per bucket, 512 threads: aggregate g[src] into x/y LDS planes, fold self-loop,
// GCN channel pass + relu; S/T2 into 8 spread replicas. (Tail split out -> k_tail1/2.)
__global__ __launch_bounds__(BAT) void k_bagg_node(const unsigned int* __restrict__ gctr,
        const unsigned int* __restrict__ payload,
        const float* __restrict__ g, const float* __restrict__ rsv,
        const float* __restrict__ gcn_w, const float* __restrict__ gcn_b,
        float* __restrict__ S8, float* __restrict__ T2_8) {
    __shared__ float agg[NPB * 2];
    __shared__ float shSf[HH];
    __shared__ float shw[8];
    const int b = blockIdx.x, t = threadIdx.x;
    agg[t] = 0.f;                   // BAT == NPB*2
    if (t < HH) shSf[t] = 0.f;
    __syncthreads();
    const unsigned int cnt = min(gctr[b], (unsigned int)MAXPB);
    const unsigned int* pl = payload + (size_t)b * MAXPB;
    const uint4* pl4 = reinterpret_cast<const uint4*>(pl);
    const unsigned int nv = cnt >> 2;

    #define ACC(P) { \
        unsigned int s_ = (P) >> BSH, dl_ = (P) & (NPB - 1); \
        float2 gv_ = *reinterpret_cast<const float2*>(&g[2 * s_]); \
        atomicAdd(&agg[dl_],       gv_.x); \
        atomicAdd(&agg[NPB + dl_], gv_.y); }

    {
        const unsigned int k1 = t, k2 = t + BAT;
        uint4 p1, p2;
        const bool v1 = k1 < nv, v2 = k2 < nv;
        if (v1) p1 = pl4[k1];
        if (v2) p2 = pl4[k2];
        if (v1) { ACC(p1.x) ACC(p1.y) ACC(p1.z) ACC(p1.w) }
        if (v2) { ACC(p2.x) ACC(p2.y) ACC(p2.z) ACC(p2.w) }
    }
    for (unsigned int k = t + 2 * BAT; k < nv; k += BAT) {
        uint4 p = pl4[k];
        ACC(p.x) ACC(p.y) ACC(p.z) ACC(p.w)
    }
    for (unsigned int k = (nv << 2) + t; k < cnt; k += BAT) {
        unsigned int p = pl[k];
        ACC(p)
    }
    #undef ACC
    __syncthreads();

    const int nvalid = min(NPB, NN - (b << BSH));
    if (t < nvalid) {
        int node = (b << BSH) + t;
        float rs = rsv[node];
        float2 gv = *reinterpret_cast<const float2*>(&g[2 * node]);
        agg[t]       = rs * (agg[t]       + gv.x);
        agg[NPB + t] = rs * (agg[NPB + t] + gv.y);
    }
    __syncthreads();

    const int ch = t & (HH - 1), slot = t >> 7;   // slot 0..3
    const float w0 = gcn_w[ch], w1 = gcn_w[HH + ch], bb = gcn_b[ch];
    float accS = 0.f, accT2 = 0.f;
    for (int j = slot; j < nvalid; j += 4) {
        float x = fmaf(agg[j], w0, fmaf(agg[NPB + j], w1, bb));
        float r = fmaxf(x, 0.f);
        accS  += r;
        accT2 += r * r;
    }
    atomicAdd(&shSf[ch], accS);
    float v = accT2;
    for (int o = 32; o; o >>= 1) v += __shfl_down(v, o, 64);
    if ((t & 63) == 0) shw[t >> 6] = v;
    __syncthreads();
    const int rep = b & (NSREP - 1);
    if (t < HH) atomicAdd(&S8[rep * HH + t], shSf[t]);
    if (t == 0) {
        float s2 = 0.f;
        #pragma unroll
        for (int w = 0; w < 8; ++w) s2 += shw[w];
        atomicAdd(&T2_8[rep], s2);
    }
}

// 16 WGs x 128 threads: WG i handles k-rows [8i, 8i+8) of fc1_w[0:128].
// upart = W1^T (ln_w . S) slice; c1part = W1^T ln_w slice; c2part = W1^T ln_b slice.
// Kernel boundary after bagg publishes S8 (same mechanism as payload pipeline).
__global__ __launch_bounds__(128) void k_tail1(const float* __restrict__ S8,
                                               const float* __restrict__ ln_w,
                                               const float* __restrict__ ln_b,
                                               const float* __restrict__ fc1_w,
                                               float* __restrict__ upart,
                                               float* __restrict__ c1part,
                                               float* __restrict__ c2part) {
    const int i = blockIdx.x, t = threadIdx.x;
    __shared__ float sh_sw[8], sh_lw[8], sh_lb[8];
    if (t < 8) {
        const int k = i * 8 + t;
        float s = 0.f;
        #pragma unroll
        for (int r = 0; r < NSREP; ++r) s += S8[r * HH + k];
        float lw = ln_w[k];
        sh_sw[t] = lw * s;
        sh_lw[t] = lw;
        sh_lb[t] = ln_b[k];
    }
    __syncthreads();
    float u = 0.f, c1 = 0.f, c2 = 0.f;
    #pragma unroll
    for (int kk = 0; kk < 8; ++kk) {
        float w = fc1_w[(size_t)(i * 8 + kk) * HH + t];
        u  = fmaf(sh_sw[kk], w, u);
        c1 = fmaf(sh_lw[kk], w, c1);
        c2 = fmaf(sh_lb[kk], w, c2);
    }
    upart[(size_t)i * HH + t]  = u;
    c1part[(size_t)i * HH + t] = c1;
    c2part[(size_t)i * HH + t] = c2;
}

// 1 WG x 128 threads: T1/T2 reduce, LN constants, combine partials, fc2, log_softmax.
__global__ __launch_bounds__(128) void k_tail2(const float* __restrict__ S8,
                                               const float* __restrict__ T2_8,
                                               const float* __restrict__ upart,
                                               const float* __restrict__ c1part,
                                               const float* __restrict__ c2part,
                                               const float* __restrict__ zpart,
                                               const float* __restrict__ fc1_b,
                                               const float* __restrict__ fc2_w,
                                               const float* __restrict__ fc2_b,
                                               float* __restrict__ out) {
    const int t = threadIdx.x;
    __shared__ float sh_z[HH], sh_logits[AA], shred[2], sh_t2[8];

    float s = 0.f;
    #pragma unroll
    for (int r = 0; r < NSREP; ++r) s += S8[r * HH + t];
    float vv = s;
    for (int o = 32; o; o >>= 1) vv += __shfl_down(vv, o, 64);
    if ((t & 63) == 0) shred[t >> 6] = vv;
    if (t < 8) sh_t2[t] = T2_8[t];
    __syncthreads();

    const float T1 = shred[0] + shred[1];
    float T2v = 0.f;
    #pragma unroll
    for (int r = 0; r < 8; ++r) T2v += sh_t2[r];
    const float cntf = (float)NN * (float)HH;
    const float mean = T1 / cntf;
    const float var  = T2v / cntf - mean * mean;
    const float denom = sqrtf(var) + LN_EPS;
    const float inv_denom = 1.0f / denom;
    const float nmean = (float)NN * mean;

    float u = 0.f, c1 = 0.f, c2 = 0.f, zs = 0.f;
    #pragma unroll
    for (int i = 0; i < NTW; ++i) {
        u  += upart[(size_t)i * HH + t];
        c1 += c1part[(size_t)i * HH + t];
        c2 += c2part[(size_t)i * HH + t];
        zs += zpart[(size_t)i * HH + t];
    }
    // fc1_pooled = (u - N*mean*c1)/denom + N*c2
    float fc1p = (u - nmean * c1) * inv_denom + (float)NN * c2;
    sh_z[t] = fmaxf(fc1p + zs + fc1_b[t], 0.f);
    __syncthreads();

    if (t < AA) {
        float l = fc2_b[t];
        for (int j = 0; j < HH; ++j)
            l = fmaf(sh_z[j], fc2_w[j * AA + t], l);
        sh_logits[t] = l;
    }
    __syncthreads();

    if (t == 0) {
        float m = sh_logits[0];
        for (int a = 1; a < AA; ++a) m = fmaxf(m, sh_logits[a]);
        float sum = 0.f;
        for (int a = 0; a < AA; ++a) sum += expf(sh_logits[a] - m);
        float lse = m + logf(sum);
        for (int a = 0; a < AA; ++a) out[a] = sh_logits[a] - lse;
    }
}

// ---------------- fallback path (round-2 known-good) ----------------

__global__ void k_initf(unsigned int* __restrict__ p, int n) {
    int i = blockIdx.x * blockDim.x + threadIdx.x;
    int stride = gridDim.x * blockDim.x;
    for (int j = i; j < n; j += stride) p[j] = 0u;
}

__global__ void k_deg1(const int* __restrict__ dst, int* __restrict__ deg, int e) {
    int i = blockIdx.x * blockDim.x + threadIdx.x;
    if (i < e) atomicAdd(&deg[dst[i]], 1);
}

__global__ void k_g1(const int* __restrict__ deg, const float* __restrict__ nf,
                     float* __restrict__ degf, float* __restrict__ g, int n) {
    int i = blockIdx.x * blockDim.x + threadIdx.x;
    if (i < n) {
        float df = (float)(1 + deg[i]);
        degf[i] = df;
        float rs = rsqrtf(df);
        float2 f = *reinterpret_cast<const float2*>(&nf[2 * i]);
        float2 gv; gv.x = rs * f.x; gv.y = rs * f.y;
        *reinterpret_cast<float2*>(&g[2 * i]) = gv;
    }
}

__global__ void k_edge1(const int* __restrict__ src, const int* __restrict__ dst,
                        const float* __restrict__ g, float* __restrict__ B, int e) {
    int i = blockIdx.x * blockDim.x + threadIdx.x;
    if (i < e) {
        int s = src[i], d = dst[i];
        float2 gv = *reinterpret_cast<const float2*>(&g[2 * s]);
        atomicAdd(&B[2 * d],     gv.x);
        atomicAdd(&B[2 * d + 1], gv.y);
    }
}

__global__ void k_node(const float* __restrict__ nf, const float* __restrict__ degf,
                       const float* __restrict__ B,
                       const float* __restrict__ gcn_w, const float* __restrict__ gcn_b,
                       float* __restrict__ S, float* __restrict__ T2, int n) {
    const int ch   = threadIdx.x & (HH - 1);
    const int slot = threadIdx.x >> 7;
    const float w0 = gcn_w[ch];
    const float w1 = gcn_w[HH + ch];
    const float b  = gcn_b[ch];
    float accS = 0.f, accT2 = 0.f;
    for (int i = blockIdx.x * 2 + slot; i < n; i += gridDim.x * 2) {
        float df   = degf[i];
        float invd = 1.0f / df;
        float rs   = rsqrtf(df);
        float2 bv = *reinterpret_cast<const float2*>(&B[2 * i]);
        float2 f  = *reinterpret_cast<const float2*>(&nf[2 * i]);
        float b0 = rs * bv.x + f.x * invd;
        float b1 = rs * bv.y + f.y * invd;
        float xv = fmaf(b0, w0, fmaf(b1, w1, b));
        float r  = fmaxf(xv, 0.f);
        accS  += r;
        accT2 += r * r;
    }
    __shared__ float shS[HH];
    if (slot == 1) shS[ch] = accS;
    __syncthreads();
    if (slot == 0) atomicAdd(&S[ch], accS + shS[ch]);
    float v = accT2;
    for (int o = 32; o; o >>= 1) v += __shfl_down(v, o, 64);
    __shared__ float shw[4];
    if ((threadIdx.x & 63) == 0) shw[threadIdx.x >> 6] = v;
    __syncthreads();
    if (threadIdx.x == 0) atomicAdd(T2, shw[0] + shw[1] + shw[2] + shw[3]);
}

__global__ void k_final(const float* __restrict__ S, const float* __restrict__ T2ptr,
                        const float* __restrict__ esn,
                        const float* __restrict__ ln_w, const float* __restrict__ ln_b,
                        const float* __restrict__ fc1_w, const float* __restrict__ fc1_b,
                        const float* __restrict__ fc2_w, const float* __restrict__ fc2_b,
                        float* __restrict__ out) {
    const int t = threadIdx.x;
    __shared__ float sh_pooled[HH];
    __shared__ float sh_z[HH];
    __shared__ float sh_logits[AA];
    __shared__ float shred[2];

    float s = S[t];
    float v = s;
    for (int o = 32; o; o >>= 1) v += __shfl_down(v, o, 64);
    if ((t & 63) == 0) shred[t >> 6] = v;
    __syncthreads();
    const float T1 = shred[0] + shred[1];
    const float T2 = *T2ptr;
    const float cnt = (float)NN * (float)HH;
    const float mean = T1 / cnt;
    const float var  = T2 / cnt - mean * mean;
    const float denom = sqrtf(var) + LN_EPS;
    sh_pooled[t] = ln_w[t] * (s - (float)NN * mean) / denom + (float)NN * ln_b[t];
    __syncthreads();

    float acc = fc1_b[t];
    for (int k = 0; k < HH; ++k)
        acc = fmaf(sh_pooled[k], fc1_w[k * HH + t], acc);
    for (int k = 0; k < RR; ++k)
        acc = fmaf(esn[k], fc1_w[(HH + k) * HH + t], acc);
    sh_z[t] = fmaxf(acc, 0.f);
    __syncthreads();

    if (t < AA) {
        float l = fc2_b[t];
        for (int j = 0; j < HH; ++j)
            l = fmaf(sh_z[j], fc2_w[j * AA + t], l);
        sh_logits[t] = l;
    }
    __syncthreads();

    if (t == 0) {
        float m = sh_logits[0];
        for (int a = 1; a < AA; ++a) m = fmaxf(m, sh_logits[a]);
        float sum = 0.f;
        for (int a = 0; a < AA; ++a) sum += expf(sh_logits[a] - m);
        float lse = m + logf(sum);
        for (int a = 0; a < AA; ++a) out[a] = sh_logits[a] - lse;
    }
}

extern "C" void kernel_launch(void* const* d_in, const int* in_sizes, int n_in,
                              void* d_out, int out_size, void* d_ws, size_t ws_size,
                              hipStream_t stream) {
    const float* nf     = (const float*)d_in[0];
    const int*   ei     = (const int*)d_in[1];
    const float* esn    = (const float*)d_in[2];
    const float* gcn_w  = (const float*)d_in[3];
    const float* gcn_b  = (const float*)d_in[4];
    const float* ln_w   = (const float*)d_in[5];
    const float* ln_b   = (const float*)d_in[6];
    const float* fc1_w  = (const float*)d_in[7];
    const float* fc1_b  = (const float*)d_in[8];
    const float* fc2_w  = (const float*)d_in[9];
    const float* fc2_b  = (const float*)d_in[10];
    float* out = (float*)d_out;
    float* ws  = (float*)d_ws;

    // Layout (word offsets):
    //   gctr:0(512) | S8:512(1024) | T2_8:1536(8) | upart:1544(2048) | c1part:3592(2048)
    //   | c2part:5640(2048) | zpart:7688(2048) | payload:9736(NB*MAXPB) | rsv(NN) | g(2NN)
    const size_t OFF_S8      = 512;
    const size_t OFF_T28     = OFF_S8 + NSREP * HH;      // 1536
    const size_t OFF_UPART   = OFF_T28 + 8;              // 1544
    const size_t OFF_C1      = OFF_UPART + (size_t)NTW * HH;   // 3592
    const size_t OFF_C2      = OFF_C1 + (size_t)NTW * HH;      // 5640
    const size_t OFF_ZPART   = OFF_C2 + (size_t)NTW * HH;      // 7688
    const size_t OFF_PAYLOAD = OFF_ZPART + (size_t)NZW * HH;   // 9736 (mult of 4)
    const size_t OFF_RSV     = OFF_PAYLOAD + (size_t)NB * MAXPB;
    const size_t OFF_G       = OFF_RSV + NN;             // even -> float2 ok
    const size_t NEED_BKT    = (OFF_G + 2 * (size_t)NN) * 4;

    if (ws_size >= NEED_BKT) {
        unsigned int* gctr    = (unsigned int*)ws;
        float*        S8      = ws + OFF_S8;
        float*        T2_8    = ws + OFF_T28;
        float*        upart   = ws + OFF_UPART;
        float*        c1part  = ws + OFF_C1;
        float*        c2part  = ws + OFF_C2;
        float*        zpart   = ws + OFF_ZPART;
        unsigned int* payload = (unsigned int*)ws + OFF_PAYLOAD;
        float*        rsv     = ws + OFF_RSV;
        float*        g       = ws + OFF_G;

        hipLaunchKernelGGL(k_init_esn,  dim3(NZW + 1), dim3(256),  0, stream,
                           (unsigned int*)ws, esn, fc1_w, zpart);
        hipLaunchKernelGGL(k_scatter,   dim3(NWG_SC),  dim3(SCT),  0, stream, ei, ei + EE, gctr, payload);
        hipLaunchKernelGGL(k_bdeg_g,    dim3(NB),      dim3(1024), 0, stream, gctr, payload, nf, rsv, g);
        hipLaunchKernelGGL(k_bagg_node, dim3(NB),      dim3(BAT),  0, stream,
                           gctr, payload, g, rsv, gcn_w, gcn_b, S8, T2_8);
        hipLaunchKernelGGL(k_tail1,     dim3(NTW),     dim3(128),  0, stream,
                           S8, ln_w, ln_b, fc1_w, upart, c1part, c2part);
        hipLaunchKernelGGL(k_tail2,     dim3(1),       dim3(128),  0, stream,
                           S8, T2_8, upart, c1part, c2part, zpart, fc1_b, fc2_w, fc2_b, out);
    } else {
        // Fallback: known-good atomic path.
        int*   deg  = (int*)ws;
        float* B    = ws + NN;
        float* S    = ws + 3 * (size_t)NN;
        float* T2   = ws + 3 * (size_t)NN + 128;
        float* degf = ws + 3 * (size_t)NN + 130;
        float* g    = ws + 4 * (size_t)NN + 130;
        const int eb = (EE + 255) / 256;
        const int nb = (NN + 255) / 256;
        hipLaunchKernelGGL(k_initf, dim3(2048), dim3(256), 0, stream, (unsigned int*)ws, 3 * NN + 129);
        hipLaunchKernelGGL(k_deg1,  dim3(eb),   dim3(256), 0, stream, ei + EE, deg, EE);
        hipLaunchKernelGGL(k_g1,    dim3(nb),   dim3(256), 0, stream, deg, nf, degf, g, NN);
        hipLaunchKernelGGL(k_edge1, dim3(eb),   dim3(256), 0, stream, ei, ei + EE, g, B, EE);
        hipLaunchKernelGGL(k_node,  dim3(512),  dim3(256), 0, stream, nf, degf, B, gcn_w, gcn_b, S, T2, NN);
        hipLaunchKernelGGL(k_final, dim3(1),    dim3(128), 0, stream,
                           S, T2, esn, ln_w, ln_b, fc1_w, fc1_b, fc2_w, fc2_b, out);
    }
}